// Round 4
// baseline (14338.029 us; speedup 1.0000x reference)
//
#include <hip/hip_runtime.h>
#include <math.h>

#define TT 2048
#define II 64
#define HH 512
#define LL 5
#define RING 8
#define BPL 32               // blocks per layer
#define NBLK (LL * BPL)      // 160
#define WPB 8                // waves per block (512 threads)
#define JPW 2                // h-outputs per wave

typedef unsigned long long u64;

__device__ __forceinline__ float wave_sum(float v) {
#pragma unroll
  for (int m = 32; m > 0; m >>= 1) v += __shfl_xor(v, m, 64);
  return v;
}

__device__ __forceinline__ float wave_max(float v) {
#pragma unroll
  for (int m = 32; m > 0; m >>= 1) v = fmaxf(v, __shfl_xor(v, m, 64));
  return v;
}

__device__ __forceinline__ float sigmoidf_(float v) {
  return 1.0f / (1.0f + expf(-v));
}

__device__ __forceinline__ u64 ld8(const u64* p) {
  return __hip_atomic_load((u64*)p, __ATOMIC_RELAXED, __HIP_MEMORY_SCOPE_AGENT);
}
__device__ __forceinline__ void st8(u64* p, u64 v) {
  __hip_atomic_store(p, v, __ATOMIC_RELAXED, __HIP_MEMORY_SCOPE_AGENT);
}
__device__ __forceinline__ unsigned ld4(const unsigned* p) {
  return __hip_atomic_load((unsigned*)p, __ATOMIC_RELAXED, __HIP_MEMORY_SCOPE_AGENT);
}

__device__ __forceinline__ void wait_ge(unsigned* p, unsigned v) {
  long spins = 0;
  while (ld4(p) < v) {
    if (++spins > 8000000L) {
      __hip_atomic_fetch_max(p, v, __ATOMIC_RELAXED, __HIP_MEMORY_SCOPE_AGENT);
      break;
    }
  }
}

// Monotone full-grid barrier — readout phase transitions only (3 uses).
__device__ __forceinline__ void grid_barrier(unsigned* arrive, unsigned* gen, unsigned idx) {
  __syncthreads();
  if (threadIdx.x == 0) {
    __threadfence();  // release (wbl2 flushes this XCD's dirty lines)
    unsigned target = (unsigned)NBLK * (idx + 1u);
    unsigned prev = __hip_atomic_fetch_add(arrive, 1u, __ATOMIC_RELAXED, __HIP_MEMORY_SCOPE_AGENT);
    if (prev + 1u == target) {
      __hip_atomic_store(gen, idx + 1u, __ATOMIC_RELAXED, __HIP_MEMORY_SCOPE_AGENT);
    } else {
      wait_ge(gen, idx + 1u);
    }
    __threadfence();  // acquire (inv)
  }
  __syncthreads();
}

extern "C" __global__ void __launch_bounds__(512, 2) lstm_pipe(
    const float* __restrict__ x,
    const float* __restrict__ w_ih0, const float* __restrict__ w_hh0,
    const float* __restrict__ b_ih0, const float* __restrict__ b_hh0,
    const float* __restrict__ w_ih, const float* __restrict__ w_hh,
    const float* __restrict__ b_ih, const float* __restrict__ b_hh,
    const float* __restrict__ w_lin, const float* __restrict__ b_lin,
    float* __restrict__ out, float* __restrict__ ws) {
  // counter area (first 4 KB, memset to 0): prog[l] at cnt[l*64] (l=1..4),
  // garr at cnt[320], ggen at cnt[336]
  unsigned* cnt = (unsigned*)ws;
  // data area (8B-aligned, starts at +4 KB):
  u64* ring = (u64*)(ws + 1024);                  // [LL][RING][HH] tagged pairs
  float* h4 = (float*)(ring + (size_t)LL * RING * HH);   // TT*HH
  float* h4T = h4 + (size_t)TT * HH;              // HH*TT
  float* scores = h4T + (size_t)HH * TT;          // TT
  float* pbuf = scores + TT;                      // TT
  float* red = pbuf + TT;                         // 1

  const int b = blockIdx.x;
  const int tid = threadIdx.x;
  const int wv = tid >> 6;
  const int lane = tid & 63;
  const int l = b / BPL;
  const int q = b % BPL;
  const int j0 = (q * WPB + wv) * JPW;  // this wave owns outputs j0, j0+1

  unsigned* prog_l = cnt + l * 64;
  unsigned* prog_lp1 = cnt + (l + 1) * 64;  // valid only for l < LL-1
  unsigned* garr = cnt + 320;
  unsigned* ggen = cnt + 336;

  // ---- load weights transposed: w[jj][g][m] pairs with h[m*64 + lane] ----
  float whh[JPW][4][8], wih[JPW][4][8], bias[JPW][4];
  const float* WHH = (l == 0) ? w_hh0 : (w_hh + (size_t)(l - 1) * 4 * HH * HH);
#pragma unroll
  for (int jj = 0; jj < JPW; ++jj) {
#pragma unroll
    for (int g = 0; g < 4; ++g) {
      const int row = g * HH + j0 + jj;
#pragma unroll
      for (int m = 0; m < 8; ++m) whh[jj][g][m] = WHH[(size_t)row * HH + m * 64 + lane];
    }
  }
  if (l == 0) {
#pragma unroll
    for (int jj = 0; jj < JPW; ++jj) {
#pragma unroll
      for (int g = 0; g < 4; ++g) {
        const int row = g * HH + j0 + jj;
        wih[jj][g][0] = w_ih0[(size_t)row * II + lane];
#pragma unroll
        for (int m = 1; m < 8; ++m) wih[jj][g][m] = 0.0f;
        bias[jj][g] = b_ih0[row] + b_hh0[row];
      }
    }
  } else {
    const float* WIH = w_ih + (size_t)(l - 1) * 4 * HH * HH;
    const float* BIH = b_ih + (size_t)(l - 1) * 4 * HH;
    const float* BHH = b_hh + (size_t)(l - 1) * 4 * HH;
#pragma unroll
    for (int jj = 0; jj < JPW; ++jj) {
#pragma unroll
      for (int g = 0; g < 4; ++g) {
        const int row = g * HH + j0 + jj;
#pragma unroll
        for (int m = 0; m < 8; ++m) wih[jj][g][m] = WIH[(size_t)row * HH + m * 64 + lane];
        bias[jj][g] = BIH[row] + BHH[row];
      }
    }
  }

  u64* ringL = ring + (size_t)l * RING * HH;
  u64* ringP = ring + (size_t)(l - 1) * RING * HH;  // valid only when l > 0

  float cst[JPW];
#pragma unroll
  for (int jj = 0; jj < JPW; ++jj) cst[jj] = 0.0f;

  const bool need_prev = (l > 0);
  const bool is_last = (l == LL - 1);

  // ---- recurrence: tag-validated single-round-trip exchange, no block sync ----
  for (int t = 0; t < TT; ++t) {
    const int so = (t - 1) & (RING - 1);  // own h_{t-1} slot
    const int sp = t & (RING - 1);        // prev-layer h_t slot (also own write slot)
    const u64* own_rd = ringL + (size_t)so * HH + lane;
    const u64* prev_rd = ringP + (size_t)sp * HH + lane;
    const bool need_own = (t > 0);
    const bool need_bp = (l < LL - 1) && (t >= RING);
    const unsigned bp_min = (unsigned)(t - (RING - 2));  // prog_{l+1} >= t-6

    u64 po[8], pp[8];
    long spins = 0;
    for (;;) {
      if (need_own) {
#pragma unroll
        for (int m = 0; m < 8; ++m) po[m] = ld8(own_rd + m * 64);
      }
      if (need_prev) {
#pragma unroll
        for (int m = 0; m < 8; ++m) pp[m] = ld8(prev_rd + m * 64);
      }
      unsigned pg = need_bp ? ld4(prog_lp1) : 0xFFFFFFFFu;
      bool ok = true;
      if (need_own) {
#pragma unroll
        for (int m = 0; m < 8; ++m) ok &= ((unsigned)(po[m] >> 32) == (unsigned)t);
      }
      if (need_prev) {
#pragma unroll
        for (int m = 0; m < 8; ++m) ok &= ((unsigned)(pp[m] >> 32) == (unsigned)(t + 1));
      }
      if (need_bp) ok &= (pg >= bp_min);
      if (__ballot(ok) == ~0ull) break;
      if (++spins > 4000000L) break;  // degrade to wrong-answer, never hang
    }

    float hp[8], xin[8];
#pragma unroll
    for (int m = 0; m < 8; ++m) hp[m] = need_own ? __uint_as_float((unsigned)po[m]) : 0.0f;
    if (l == 0) {
      xin[0] = x[(size_t)t * II + lane];
#pragma unroll
      for (int m = 1; m < 8; ++m) xin[m] = 0.0f;
    } else {
#pragma unroll
      for (int m = 0; m < 8; ++m) xin[m] = __uint_as_float((unsigned)pp[m]);
    }

    float acc[JPW][4];
#pragma unroll
    for (int jj = 0; jj < JPW; ++jj)
#pragma unroll
      for (int g = 0; g < 4; ++g) acc[jj][g] = 0.0f;
#pragma unroll
    for (int m = 0; m < 8; ++m) {
      const float hv = hp[m];
#pragma unroll
      for (int jj = 0; jj < JPW; ++jj) {
        acc[jj][0] = fmaf(whh[jj][0][m], hv, acc[jj][0]);
        acc[jj][1] = fmaf(whh[jj][1][m], hv, acc[jj][1]);
        acc[jj][2] = fmaf(whh[jj][2][m], hv, acc[jj][2]);
        acc[jj][3] = fmaf(whh[jj][3][m], hv, acc[jj][3]);
      }
    }
#pragma unroll
    for (int m = 0; m < 8; ++m) {
      const float xv = xin[m];
#pragma unroll
      for (int jj = 0; jj < JPW; ++jj) {
        acc[jj][0] = fmaf(wih[jj][0][m], xv, acc[jj][0]);
        acc[jj][1] = fmaf(wih[jj][1][m], xv, acc[jj][1]);
        acc[jj][2] = fmaf(wih[jj][2][m], xv, acc[jj][2]);
        acc[jj][3] = fmaf(wih[jj][3][m], xv, acc[jj][3]);
      }
    }

    float hout[JPW];
#pragma unroll
    for (int jj = 0; jj < JPW; ++jj) {
      float ai = wave_sum(acc[jj][0]);
      float af = wave_sum(acc[jj][1]);
      float ag = wave_sum(acc[jj][2]);
      float ao = wave_sum(acc[jj][3]);
      float gi = sigmoidf_(ai + bias[jj][0]);
      float gf = sigmoidf_(af + bias[jj][1]);
      float gg = tanhf(ag + bias[jj][2]);
      float go = sigmoidf_(ao + bias[jj][3]);
      cst[jj] = gf * cst[jj] + gi * gg;
      hout[jj] = go * tanhf(cst[jj]);
    }

    if (lane == 0) {
      const u64 tag = ((u64)(unsigned)(t + 1)) << 32;
      st8(ringL + (size_t)sp * HH + j0, tag | (u64)__float_as_uint(hout[0]));
      st8(ringL + (size_t)sp * HH + j0 + 1, tag | (u64)__float_as_uint(hout[1]));
      if (is_last) {
        h4[(size_t)t * HH + j0] = hout[0];
        h4[(size_t)t * HH + j0 + 1] = hout[1];
        h4T[(size_t)j0 * TT + t] = hout[0];
        h4T[(size_t)(j0 + 1) * TT + t] = hout[1];
      }
    }
    // progress publication for back-pressure (layers 1..4, every 2 steps)
    if (l > 0 && q == 0 && wv == 0 && lane == 0 && ((t + 1) & 1) == 0) {
      __hip_atomic_store(prog_l, (unsigned)(t + 1), __ATOMIC_RELAXED, __HIP_MEMORY_SCOPE_AGENT);
    }
  }

  grid_barrier(garr, ggen, 0u);

  // ---- phase A: scores[t] = tanh(h4[t] . w_lin + b_lin) ----
  for (int t = b * WPB + wv; t < TT; t += NBLK * WPB) {
    const float4* hp4 = (const float4*)(h4 + (size_t)t * HH + lane * 8);
    const float4* wl4 = (const float4*)(w_lin + lane * 8);
    float4 a = hp4[0], d = hp4[1], wa = wl4[0], wd = wl4[1];
    float acc = 0.0f;
    acc = fmaf(a.x, wa.x, acc); acc = fmaf(a.y, wa.y, acc);
    acc = fmaf(a.z, wa.z, acc); acc = fmaf(a.w, wa.w, acc);
    acc = fmaf(d.x, wd.x, acc); acc = fmaf(d.y, wd.y, acc);
    acc = fmaf(d.z, wd.z, acc); acc = fmaf(d.w, wd.w, acc);
    acc = wave_sum(acc);
    float sc = tanhf(acc + b_lin[0]);
    if (lane == 0) scores[t] = sc;
  }
  grid_barrier(garr, ggen, 1u);

  // ---- phase B: softmax over time (block 0 only; 512 threads x 4 each) ----
  __shared__ float sbuf[12];
  if (b == 0) {
    float s0 = scores[tid], s1 = scores[tid + 512];
    float s2 = scores[tid + 1024], s3 = scores[tid + 1536];
    float m = fmaxf(fmaxf(s0, s1), fmaxf(s2, s3));
    m = wave_max(m);
    if (lane == 0) sbuf[wv] = m;
    __syncthreads();
    if (tid == 0) {
      float M = sbuf[0];
      for (int k = 1; k < 8; ++k) M = fmaxf(M, sbuf[k]);
      sbuf[8] = M;
    }
    __syncthreads();
    float M = sbuf[8];
    float p0 = expf(s0 - M), p1 = expf(s1 - M);
    float p2 = expf(s2 - M), p3 = expf(s3 - M);
    pbuf[tid] = p0; pbuf[tid + 512] = p1;
    pbuf[tid + 1024] = p2; pbuf[tid + 1536] = p3;
    float ssum = wave_sum(p0 + p1 + p2 + p3);
    __syncthreads();
    if (lane == 0) sbuf[wv] = ssum;
    __syncthreads();
    if (tid == 0) {
      float S = 0.0f;
      for (int k = 0; k < 8; ++k) S += sbuf[k];
      red[0] = 1.0f / ((float)TT * S);
    }
  }
  grid_barrier(garr, ggen, 2u);

  // ---- phase C: out[j] = scale * sum_t p_t * h4T[j][t] ----
  {
    const int gw = b * WPB + wv;
    if (gw < HH) {
      const float scale = red[0];
      const float* hr = h4T + (size_t)gw * TT + lane * 32;
      const float* pr = pbuf + lane * 32;
      float acc = 0.0f;
#pragma unroll
      for (int m = 0; m < 32; ++m) acc = fmaf(hr[m], pr[m], acc);
      acc = wave_sum(acc);
      if (lane == 0) out[gw] = scale * acc;
    }
  }
}

extern "C" void kernel_launch(void* const* d_in, const int* in_sizes, int n_in,
                              void* d_out, int out_size, void* d_ws, size_t ws_size,
                              hipStream_t stream) {
  hipMemsetAsync(d_ws, 0, 4096, stream);  // zero prog counters + barrier words
  lstm_pipe<<<dim3(NBLK), dim3(512), 0, stream>>>(
      (const float*)d_in[0],
      (const float*)d_in[1], (const float*)d_in[2],
      (const float*)d_in[3], (const float*)d_in[4],
      (const float*)d_in[5], (const float*)d_in[6],
      (const float*)d_in[7], (const float*)d_in[8],
      (const float*)d_in[9], (const float*)d_in[10],
      (float*)d_out, (float*)d_ws);
}

// Round 5
// 9429.301 us; speedup vs baseline: 1.5206x; 1.5206x over previous
//
#include <hip/hip_runtime.h>
#include <math.h>

#define TT 2048
#define II 64
#define HH 512
#define LL 5
#define RING 16
#define BPL 32               // blocks per layer
#define NBLK (LL * BPL)      // 160
#define WPB 16               // waves per block

__device__ __forceinline__ float wave_sum(float v) {
#pragma unroll
  for (int m = 32; m > 0; m >>= 1) v += __shfl_xor(v, m, 64);
  return v;
}

__device__ __forceinline__ float wave_max(float v) {
#pragma unroll
  for (int m = 32; m > 0; m >>= 1) v = fmaxf(v, __shfl_xor(v, m, 64));
  return v;
}

__device__ __forceinline__ float sigmoidf_(float v) {
  return 1.0f / (1.0f + expf(-v));
}

__device__ __forceinline__ unsigned ld_cnt(const unsigned* p) {
  return __hip_atomic_load((unsigned*)p, __ATOMIC_RELAXED, __HIP_MEMORY_SCOPE_AGENT);
}

// Bounded spin; fetch_max escape degrades residency failure to wrong-answer
// instead of hang.
__device__ __forceinline__ void wait_ge(unsigned* p, unsigned v) {
  long spins = 0;
  while (ld_cnt(p) < v) {
    if (++spins > 8000000L) {
      __hip_atomic_fetch_max(p, v, __ATOMIC_RELAXED, __HIP_MEMORY_SCOPE_AGENT);
      break;
    }
  }
}

// Coherent 4B exchange: relaxed agent-scope atomics are HW-coherent at the
// device coherence point, so no fences are needed.
__device__ __forceinline__ float ld_coh(const float* p) {
  return __hip_atomic_load((float*)p, __ATOMIC_RELAXED, __HIP_MEMORY_SCOPE_AGENT);
}
__device__ __forceinline__ void st_coh(float* p, float v) {
  __hip_atomic_store(p, v, __ATOMIC_RELAXED, __HIP_MEMORY_SCOPE_AGENT);
}

// Monotone full-grid barrier — readout phase transitions only (3 uses).
__device__ __forceinline__ void grid_barrier(unsigned* arrive, unsigned* gen, unsigned idx) {
  __syncthreads();
  if (threadIdx.x == 0) {
    __threadfence();  // release: wbl2 — flush this XCD's dirty lines
    unsigned target = (unsigned)NBLK * (idx + 1u);
    unsigned prev = __hip_atomic_fetch_add(arrive, 1u, __ATOMIC_RELAXED, __HIP_MEMORY_SCOPE_AGENT);
    if (prev + 1u == target) {
      __hip_atomic_store(gen, idx + 1u, __ATOMIC_RELAXED, __HIP_MEMORY_SCOPE_AGENT);
    } else {
      wait_ge(gen, idx + 1u);
    }
    __threadfence();  // acquire: inv
  }
  __syncthreads();
}

extern "C" __global__ void __launch_bounds__(1024)
__attribute__((amdgpu_waves_per_eu(4, 4)))  // pin occupancy: allocator gets the
                                            // full 128-VGPR budget, no spill
lstm_pipe(
    const float* __restrict__ x,
    const float* __restrict__ w_ih0, const float* __restrict__ w_hh0,
    const float* __restrict__ b_ih0, const float* __restrict__ b_hh0,
    const float* __restrict__ w_ih, const float* __restrict__ w_hh,
    const float* __restrict__ b_ih, const float* __restrict__ b_hh,
    const float* __restrict__ w_lin, const float* __restrict__ b_lin,
    float* __restrict__ out, float* __restrict__ ws) {
  // counter area (first 4 KB of ws): arr[l] at cnt[l*64] (256 B apart),
  // garr at cnt[320], ggen at cnt[336]
  unsigned* cnt = (unsigned*)ws;
  float* data = ws + 1024;  // 4 KB offset
  float* h_ring = data;                          // LL*RING*HH
  float* h4 = h_ring + LL * RING * HH;           // TT*HH
  float* h4T = h4 + (size_t)TT * HH;             // HH*TT
  float* scores = h4T + (size_t)HH * TT;         // TT
  float* pbuf = scores + TT;                     // TT
  float* red = pbuf + TT;                        // 1

  const int b = blockIdx.x;
  const int tid = threadIdx.x;
  const int wv = tid >> 6;
  const int lane = tid & 63;
  const int l = b / BPL;
  const int q = b % BPL;
  const int j = q * WPB + wv;  // h-output index owned by this wave

  unsigned* arr_l = cnt + l * 64;
  unsigned* arr_lm1 = cnt + (l - 1) * 64;  // valid only when l > 0
  unsigned* arr_lp1 = cnt + (l + 1) * 64;  // valid only when l < LL-1
  unsigned* garr = cnt + 320;
  unsigned* ggen = cnt + 336;

  // ---- load weights, transposed so h-loads coalesce: w[g][m] pairs with
  // h[m*64 + lane] ----
  float whh[4][8], wih[4][8], bias[4];
  const float* WHH = (l == 0) ? w_hh0 : (w_hh + (size_t)(l - 1) * 4 * HH * HH);
#pragma unroll
  for (int g = 0; g < 4; ++g) {
    const int row = g * HH + j;
#pragma unroll
    for (int m = 0; m < 8; ++m) whh[g][m] = WHH[(size_t)row * HH + m * 64 + lane];
  }
  if (l == 0) {
#pragma unroll
    for (int g = 0; g < 4; ++g) {
      const int row = g * HH + j;
      wih[g][0] = w_ih0[(size_t)row * II + lane];
#pragma unroll
      for (int m = 1; m < 8; ++m) wih[g][m] = 0.0f;
      bias[g] = b_ih0[row] + b_hh0[row];
    }
  } else {
    const float* WIH = w_ih + (size_t)(l - 1) * 4 * HH * HH;
    const float* BIH = b_ih + (size_t)(l - 1) * 4 * HH;
    const float* BHH = b_hh + (size_t)(l - 1) * 4 * HH;
#pragma unroll
    for (int g = 0; g < 4; ++g) {
      const int row = g * HH + j;
#pragma unroll
      for (int m = 0; m < 8; ++m) wih[g][m] = WIH[(size_t)row * HH + m * 64 + lane];
      bias[g] = BIH[row] + BHH[row];
    }
  }
  // opaque pin: defeats load-rematerialization of the weight arrays
#pragma unroll
  for (int g = 0; g < 4; ++g) {
#pragma unroll
    for (int m = 0; m < 8; ++m) {
      asm volatile("" : "+v"(whh[g][m]));
      asm volatile("" : "+v"(wih[g][m]));
    }
    asm volatile("" : "+v"(bias[g]));
  }

  const float* own_rd = h_ring + (size_t)l * RING * HH + lane;
  const float* prev_rd = h_ring + (size_t)(l - 1) * RING * HH + lane;
  float* own_wr = h_ring + (size_t)l * RING * HH + j;

  float c = 0.0f;

  // ---- recurrence: per-layer counter waits + single coherent pull ----
  for (int t = 0; t < TT; ++t) {
    // three wait conditions polled in parallel by three waves
    if (tid == 0 && t > 0) wait_ge(arr_l, (unsigned)(BPL * t));               // own h_{t-1}
    if (tid == 64 && l > 0) wait_ge(arr_lm1, (unsigned)(BPL * (t + 1)));      // input ready
    if (tid == 128 && l < LL - 1 && t >= RING)
      wait_ge(arr_lp1, (unsigned)(BPL * (t - RING + 1)));                     // ring slot free
    __syncthreads();

    float hp[8];
    if (t > 0) {
      const float* rp = own_rd + (size_t)((t - 1) & (RING - 1)) * HH;
#pragma unroll
      for (int m = 0; m < 8; ++m) hp[m] = ld_coh(rp + m * 64);
    } else {
#pragma unroll
      for (int m = 0; m < 8; ++m) hp[m] = 0.0f;
    }
    float xin[8];
    if (l == 0) {
      xin[0] = x[(size_t)t * II + lane];
#pragma unroll
      for (int m = 1; m < 8; ++m) xin[m] = 0.0f;
    } else {
      const float* rp = prev_rd + (size_t)(t & (RING - 1)) * HH;
#pragma unroll
      for (int m = 0; m < 8; ++m) xin[m] = ld_coh(rp + m * 64);
    }

    float ai = 0.0f, af = 0.0f, ag = 0.0f, ao = 0.0f;
#pragma unroll
    for (int m = 0; m < 8; ++m) {
      ai = fmaf(whh[0][m], hp[m], ai);
      af = fmaf(whh[1][m], hp[m], af);
      ag = fmaf(whh[2][m], hp[m], ag);
      ao = fmaf(whh[3][m], hp[m], ao);
    }
#pragma unroll
    for (int m = 0; m < 8; ++m) {
      ai = fmaf(wih[0][m], xin[m], ai);
      af = fmaf(wih[1][m], xin[m], af);
      ag = fmaf(wih[2][m], xin[m], ag);
      ao = fmaf(wih[3][m], xin[m], ao);
    }
    ai = wave_sum(ai); af = wave_sum(af); ag = wave_sum(ag); ao = wave_sum(ao);
    float gi = sigmoidf_(ai + bias[0]);
    float gf = sigmoidf_(af + bias[1]);
    float gg = tanhf(ag + bias[2]);
    float go = sigmoidf_(ao + bias[3]);
    c = gf * c + gi * gg;
    float h = go * tanhf(c);
    if (lane == 0) {
      st_coh(own_wr + (size_t)(t & (RING - 1)) * HH, h);
      if (l == LL - 1) {
        h4[(size_t)t * HH + j] = h;
        h4T[(size_t)j * TT + t] = h;
      }
    }
    // drain own store (coherent store completed => globally visible)
    asm volatile("s_waitcnt vmcnt(0)" ::: "memory");
    __syncthreads();
    if (tid == 0) {
      __hip_atomic_fetch_add(arr_l, 1u, __ATOMIC_RELAXED, __HIP_MEMORY_SCOPE_AGENT);
    }
  }

  grid_barrier(garr, ggen, 0u);

  // ---- phase A: scores[t] = tanh(h4[t] . w_lin + b_lin) ----
  {
    const int gw = b * WPB + wv;
    if (gw < TT) {
      const int t = gw;
      const float4* hp4 = (const float4*)(h4 + (size_t)t * HH + lane * 8);
      const float4* wl4 = (const float4*)(w_lin + lane * 8);
      float4 a = hp4[0], d = hp4[1], wa = wl4[0], wd = wl4[1];
      float acc = 0.0f;
      acc = fmaf(a.x, wa.x, acc); acc = fmaf(a.y, wa.y, acc);
      acc = fmaf(a.z, wa.z, acc); acc = fmaf(a.w, wa.w, acc);
      acc = fmaf(d.x, wd.x, acc); acc = fmaf(d.y, wd.y, acc);
      acc = fmaf(d.z, wd.z, acc); acc = fmaf(d.w, wd.w, acc);
      acc = wave_sum(acc);
      float sc = tanhf(acc + b_lin[0]);
      if (lane == 0) scores[t] = sc;
    }
  }
  grid_barrier(garr, ggen, 1u);

  // ---- phase B: softmax over time (block 0 only) ----
  __shared__ float sbuf[20];
  if (b == 0) {
    float s0 = scores[tid];
    float s1 = scores[tid + 1024];
    float m = fmaxf(s0, s1);
    m = wave_max(m);
    if (lane == 0) sbuf[wv] = m;
    __syncthreads();
    if (tid == 0) {
      float M = sbuf[0];
      for (int k = 1; k < 16; ++k) M = fmaxf(M, sbuf[k]);
      sbuf[16] = M;
    }
    __syncthreads();
    float M = sbuf[16];
    float p0 = expf(s0 - M), p1 = expf(s1 - M);
    pbuf[tid] = p0;
    pbuf[tid + 1024] = p1;
    float ssum = wave_sum(p0 + p1);
    __syncthreads();
    if (lane == 0) sbuf[wv] = ssum;
    __syncthreads();
    if (tid == 0) {
      float S = 0.0f;
      for (int k = 0; k < 16; ++k) S += sbuf[k];
      red[0] = 1.0f / ((float)TT * S);
    }
  }
  grid_barrier(garr, ggen, 2u);

  // ---- phase C: out[j] = scale * sum_t p_t * h4T[j][t] ----
  {
    const int gw = b * WPB + wv;
    if (gw < HH) {
      const int jj = gw;
      const float scale = red[0];
      const float* hr = h4T + (size_t)jj * TT + lane * 32;
      const float* pr = pbuf + lane * 32;
      float acc = 0.0f;
#pragma unroll
      for (int m = 0; m < 32; ++m) acc = fmaf(hr[m], pr[m], acc);
      acc = wave_sum(acc);
      if (lane == 0) out[jj] = scale * acc;
    }
  }
}

extern "C" void kernel_launch(void* const* d_in, const int* in_sizes, int n_in,
                              void* d_out, int out_size, void* d_ws, size_t ws_size,
                              hipStream_t stream) {
  hipMemsetAsync(d_ws, 0, 4096, stream);  // zero all sync counters
  lstm_pipe<<<dim3(NBLK), dim3(1024), 0, stream>>>(
      (const float*)d_in[0],
      (const float*)d_in[1], (const float*)d_in[2],
      (const float*)d_in[3], (const float*)d_in[4],
      (const float*)d_in[5], (const float*)d_in[6],
      (const float*)d_in[7], (const float*)d_in[8],
      (const float*)d_in[9], (const float*)d_in[10],
      (float*)d_out, (float*)d_ws);
}

// Round 7
// 7642.609 us; speedup vs baseline: 1.8761x; 1.2338x over previous
//
#include <hip/hip_runtime.h>
#include <math.h>

#define TT 2048
#define II 64
#define HH 512
#define LL 5
#define RING 16
#define BPL 32                // blocks per layer
#define NBLK (LL * BPL)       // 160
#define WPB 16                // waves per block
#define SPIN_LIMIT 2000000L

typedef unsigned long long u64;
typedef unsigned u32;

__device__ __forceinline__ float wave_sum(float v) {
#pragma unroll
  for (int m = 32; m > 0; m >>= 1) v += __shfl_xor(v, m, 64);
  return v;
}

__device__ __forceinline__ float wave_max(float v) {
#pragma unroll
  for (int m = 32; m > 0; m >>= 1) v = fmaxf(v, __shfl_xor(v, m, 64));
  return v;
}

__device__ __forceinline__ float sigmoidf_(float v) {
  return 1.0f / (1.0f + expf(-v));
}

// MALL-coherent (agent-scope relaxed) accessors — proven transport (r3/r5)
__device__ __forceinline__ u32 ld4(const u32* p) {
  return __hip_atomic_load((u32*)p, __ATOMIC_RELAXED, __HIP_MEMORY_SCOPE_AGENT);
}
__device__ __forceinline__ void st4(u32* p, u32 v) {
  __hip_atomic_store(p, v, __ATOMIC_RELAXED, __HIP_MEMORY_SCOPE_AGENT);
}
__device__ __forceinline__ u64 ld8(const u64* p) {
  return __hip_atomic_load((u64*)p, __ATOMIC_RELAXED, __HIP_MEMORY_SCOPE_AGENT);
}
__device__ __forceinline__ void st8(u64* p, u64 v) {
  __hip_atomic_store(p, v, __ATOMIC_RELAXED, __HIP_MEMORY_SCOPE_AGENT);
}

__device__ __forceinline__ void wait_ge(u32* p, u32 v) {
  long spins = 0;
  while (ld4(p) < v) {
    if (++spins > SPIN_LIMIT) {
      __hip_atomic_fetch_max(p, v, __ATOMIC_RELAXED, __HIP_MEMORY_SCOPE_AGENT);
      break;
    }
  }
}

// Monotone full-grid barrier — readout phase transitions only (3 uses).
__device__ __forceinline__ void grid_barrier(u32* arrive, u32* gen, u32 idx) {
  __syncthreads();
  if (threadIdx.x == 0) {
    __threadfence();  // release
    u32 target = (u32)NBLK * (idx + 1u);
    u32 prev = __hip_atomic_fetch_add(arrive, 1u, __ATOMIC_RELAXED, __HIP_MEMORY_SCOPE_AGENT);
    if (prev + 1u == target) {
      __hip_atomic_store(gen, idx + 1u, __ATOMIC_RELAXED, __HIP_MEMORY_SCOPE_AGENT);
    } else {
      wait_ge(gen, idx + 1u);
    }
    __threadfence();  // acquire
  }
  __syncthreads();
}

extern "C" __global__ void __launch_bounds__(1024)
__attribute__((amdgpu_waves_per_eu(4, 4)))
lstm_pipe(
    const float* __restrict__ x,
    const float* __restrict__ w_ih0, const float* __restrict__ w_hh0,
    const float* __restrict__ b_ih0, const float* __restrict__ b_hh0,
    const float* __restrict__ w_ih, const float* __restrict__ w_hh,
    const float* __restrict__ b_ih, const float* __restrict__ b_hh,
    const float* __restrict__ w_lin, const float* __restrict__ b_lin,
    float* __restrict__ out, float* __restrict__ ws) {
  extern __shared__ float wihs[];   // [WPB][4][HH] = 128 KB dynamic
  __shared__ float hbuf[HH];        // staged own-layer h_{t-1}
  __shared__ float xbuf[HH];        // staged prev-layer h_t (or x_t)
  __shared__ float sbuf[20];

  // counters (first 4 KB of ws, memset 0): prog[l] at cnt[l*64];
  // garr at cnt[320]; ggen at cnt[336]
  u32* cnt = (u32*)ws;
  u32* garr = cnt + 320;
  u32* ggen = cnt + 336;

  // tagged h ring: [LL][RING][HH] u64 — (tag=t+1)<<32 | bits(h).
  // ws is poisoned 0xAA each launch: poison tag never matches a real tag.
  u64* ring = (u64*)((char*)ws + 4096);
  float* h4 = (float*)(ring + (size_t)LL * RING * HH);   // TT*HH
  float* h4T = h4 + (size_t)TT * HH;                     // HH*TT
  float* scores = h4T + (size_t)HH * TT;                 // TT
  float* pbuf = scores + TT;                             // TT
  float* red = pbuf + TT;                                // 1

  const int b = blockIdx.x;
  const int tid = threadIdx.x;
  const int wv = tid >> 6;
  const int lane = tid & 63;
  const int layer = b / BPL;
  const int slot = b % BPL;
  const int j = slot * WPB + wv;   // h-output owned by this wave
  const bool is_last = (layer == LL - 1);

  u32* prog_l = cnt + layer * 64;
  u32* prog_lp1 = cnt + (layer + 1) * 64;  // valid only when layer < LL-1
  u64* myring = ring + (size_t)layer * RING * HH;
  u64* prevring = ring + (size_t)(layer > 0 ? layer - 1 : 0) * RING * HH;

  // ---- weights: whh + bias in registers; wih in LDS ----
  float whh[4][8], bias[4];
  {
    const float* WHH = (layer == 0) ? w_hh0 : (w_hh + (size_t)(layer - 1) * 4 * HH * HH);
#pragma unroll
    for (int g = 0; g < 4; ++g) {
      const int row = g * HH + j;
#pragma unroll
      for (int m = 0; m < 8; ++m) whh[g][m] = WHH[(size_t)row * HH + m * 64 + lane];
    }
    if (layer == 0) {
#pragma unroll
      for (int g = 0; g < 4; ++g) bias[g] = b_ih0[g * HH + j] + b_hh0[g * HH + j];
    } else {
      const float* BIH = b_ih + (size_t)(layer - 1) * 4 * HH;
      const float* BHH = b_hh + (size_t)(layer - 1) * 4 * HH;
#pragma unroll
      for (int g = 0; g < 4; ++g) bias[g] = BIH[g * HH + j] + BHH[g * HH + j];
    }
    // wih -> LDS, layout [jj][g][k]; values match r5's wih[g][m]=W[row][m*64+lane]
    const float* WIH = (layer == 0) ? (const float*)0
                                    : (w_ih + (size_t)(layer - 1) * 4 * HH * HH);
    for (int f = tid; f < WPB * 4 * HH; f += 1024) {
      const int jj = f >> 11;          // /2048
      const int g = (f >> 9) & 3;
      const int k = f & 511;
      const int row = g * HH + slot * WPB + jj;
      float v;
      if (layer == 0) v = (k < II) ? w_ih0[(size_t)row * II + k] : 0.0f;
      else v = WIH[(size_t)row * HH + k];
      wihs[f] = v;
    }
    // pin whh/bias (defeat load-rematerialization)
#pragma unroll
    for (int g = 0; g < 4; ++g) {
#pragma unroll
      for (int m = 0; m < 8; ++m) asm volatile("" : "+v"(whh[g][m]));
      asm volatile("" : "+v"(bias[g]));
    }
  }
  __syncthreads();

  float c = 0.0f;

  // ---- recurrence: block-level LDS staging, tag-validated MALL exchange ----
  for (int t = 0; t < TT; ++t) {
    const int sl = t & (RING - 1);
    // staging: threads 0..511 pull own h_{t-1}; 512..1023 pull input h_t / x_t
    if (tid < HH) {
      if (t > 0) {
        const u64* p = myring + (size_t)((t - 1) & (RING - 1)) * HH + tid;
        u64 v; long sp = 0;
        do { v = ld8(p); } while ((u32)(v >> 32) != (u32)t && ++sp < SPIN_LIMIT);
        hbuf[tid] = __uint_as_float((u32)v);
      } else {
        hbuf[tid] = 0.0f;
      }
      if (tid == 0) {
        // publish consumption proof: own tags t validated => all layer blocks
        // staged step t-1 => consumed producer tags <= t  (valid for t >= 1)
        if (slot == 0 && t > 0) st4(prog_l, (u32)t);
        // back-pressure: our step-t store overwrites tag t-15; need layer+1
        // to have consumed it (prog >= t-15), 15-step slack
        if (layer < LL - 1 && t >= RING) {
          long sp = 0;
          while (ld4(prog_lp1) < (u32)(t - (RING - 1)) && ++sp < SPIN_LIMIT) {}
        }
      }
    } else {
      const int k = tid - HH;
      if (layer == 0) {
        xbuf[k] = (k < II) ? x[(size_t)t * II + k] : 0.0f;
      } else {
        const u64* p = prevring + (size_t)sl * HH + k;
        u64 v; long sp = 0;
        do { v = ld8(p); } while ((u32)(v >> 32) != (u32)(t + 1) && ++sp < SPIN_LIMIT);
        xbuf[k] = __uint_as_float((u32)v);
      }
    }
    __syncthreads();

    // compute — identical FMA/reduction order to r5 (absmax 0)
    float hp[8], xin[8];
#pragma unroll
    for (int m = 0; m < 8; ++m) {
      hp[m] = hbuf[m * 64 + lane];
      xin[m] = xbuf[m * 64 + lane];
    }
    float ai = 0.0f, af = 0.0f, ag = 0.0f, ao = 0.0f;
#pragma unroll
    for (int m = 0; m < 8; ++m) {
      ai = fmaf(whh[0][m], hp[m], ai);
      af = fmaf(whh[1][m], hp[m], af);
      ag = fmaf(whh[2][m], hp[m], ag);
      ao = fmaf(whh[3][m], hp[m], ao);
    }
    const float* wb = wihs + (size_t)wv * 4 * HH;
#pragma unroll
    for (int m = 0; m < 8; ++m) {
      const int o = m * 64 + lane;
      ai = fmaf(wb[0 * HH + o], xin[m], ai);
      af = fmaf(wb[1 * HH + o], xin[m], af);
      ag = fmaf(wb[2 * HH + o], xin[m], ag);
      ao = fmaf(wb[3 * HH + o], xin[m], ao);
    }
    ai = wave_sum(ai); af = wave_sum(af); ag = wave_sum(ag); ao = wave_sum(ao);
    float gi = sigmoidf_(ai + bias[0]);
    float gf = sigmoidf_(af + bias[1]);
    float gg = tanhf(ag + bias[2]);
    float go = sigmoidf_(ao + bias[3]);
    c = gf * c + gi * gg;
    float h = go * tanhf(c);

    if (lane == 0) {
      st8(myring + (size_t)sl * HH + j,
          (((u64)(u32)(t + 1)) << 32) | (u64)__float_as_uint(h));
      if (is_last) {
        h4[(size_t)t * HH + j] = h;
        h4T[(size_t)j * TT + t] = h;
      }
    }
    __syncthreads();  // protect hbuf/xbuf from next step's staging
  }

  grid_barrier(garr, ggen, 0u);

  // ---- phase A: scores[t] = tanh(h4[t] . w_lin + b_lin) ----
  {
    const int gw = b * WPB + wv;
    if (gw < TT) {
      const int t = gw;
      const float4* hp4 = (const float4*)(h4 + (size_t)t * HH + lane * 8);
      const float4* wl4 = (const float4*)(w_lin + lane * 8);
      float4 a = hp4[0], d = hp4[1], wa = wl4[0], wd = wl4[1];
      float acc = 0.0f;
      acc = fmaf(a.x, wa.x, acc); acc = fmaf(a.y, wa.y, acc);
      acc = fmaf(a.z, wa.z, acc); acc = fmaf(a.w, wa.w, acc);
      acc = fmaf(d.x, wd.x, acc); acc = fmaf(d.y, wd.y, acc);
      acc = fmaf(d.z, wd.z, acc); acc = fmaf(d.w, wd.w, acc);
      acc = wave_sum(acc);
      float sc = tanhf(acc + b_lin[0]);
      if (lane == 0) scores[t] = sc;
    }
  }
  grid_barrier(garr, ggen, 1u);

  // ---- phase B: softmax over time (block 0 only) ----
  if (b == 0) {
    float s0 = scores[tid];
    float s1 = scores[tid + 1024];
    float m = fmaxf(s0, s1);
    m = wave_max(m);
    if (lane == 0) sbuf[wv] = m;
    __syncthreads();
    if (tid == 0) {
      float M = sbuf[0];
      for (int k = 1; k < 16; ++k) M = fmaxf(M, sbuf[k]);
      sbuf[16] = M;
    }
    __syncthreads();
    float M = sbuf[16];
    float p0 = expf(s0 - M), p1 = expf(s1 - M);
    pbuf[tid] = p0;
    pbuf[tid + 1024] = p1;
    float ssum = wave_sum(p0 + p1);
    __syncthreads();
    if (lane == 0) sbuf[wv] = ssum;
    __syncthreads();
    if (tid == 0) {
      float S = 0.0f;
      for (int k = 0; k < 16; ++k) S += sbuf[k];
      red[0] = 1.0f / ((float)TT * S);
    }
  }
  grid_barrier(garr, ggen, 2u);

  // ---- phase C: out[j] = scale * sum_t p_t * h4T[j][t] ----
  {
    const int gw = b * WPB + wv;
    if (gw < HH) {
      const float scale = red[0];
      const float* hr = h4T + (size_t)gw * TT + lane * 32;
      const float* pr = pbuf + lane * 32;
      float acc = 0.0f;
#pragma unroll
      for (int m = 0; m < 32; ++m) acc = fmaf(hr[m], pr[m], acc);
      acc = wave_sum(acc);
      if (lane == 0) out[gw] = scale * acc;
    }
  }
}

extern "C" void kernel_launch(void* const* d_in, const int* in_sizes, int n_in,
                              void* d_out, int out_size, void* d_ws, size_t ws_size,
                              hipStream_t stream) {
  hipFuncSetAttribute((const void*)lstm_pipe,
                      hipFuncAttributeMaxDynamicSharedMemorySize, 131072);
  hipMemsetAsync(d_ws, 0, 4096, stream);  // zero sync counters
  lstm_pipe<<<dim3(NBLK), dim3(1024), 131072, stream>>>(
      (const float*)d_in[0],
      (const float*)d_in[1], (const float*)d_in[2],
      (const float*)d_in[3], (const float*)d_in[4],
      (const float*)d_in[5], (const float*)d_in[6],
      (const float*)d_in[7], (const float*)d_in[8],
      (const float*)d_in[9], (const float*)d_in[10],
      (float*)d_out, (float*)d_ws);
}